// Round 3
// baseline (390.565 us; speedup 1.0000x reference)
//
#include <hip/hip_runtime.h>

// B=4, T=1024, C=16, D=256, P=4096.  Float tensors fp32; x_mask u8; pos i32.
// ws: q[bc][t][d] bf16 32MB | k[bc][t][d] bf16 32MB | vt[bc][d][t] bf16 32MB
//     | wb[3][256][256] bf16 384KB | mbg[64][1024] f32 256KB

typedef __attribute__((ext_vector_type(8))) short short8_t;
typedef __attribute__((ext_vector_type(4))) short short4_t;
typedef __attribute__((ext_vector_type(8))) float float8_t;
typedef __attribute__((ext_vector_type(4))) float float4_t;
typedef __attribute__((ext_vector_type(2))) float float2_t;

__device__ __forceinline__ float b2f(short s) {
    union { unsigned int u; float f; } x;
    x.u = ((unsigned int)(unsigned short)s) << 16;
    return x.f;
}
__device__ __forceinline__ short f2bt(float f) {   // truncate: ample headroom here
    union { float f; unsigned int u; } x; x.f = f;
    return (short)(x.u >> 16);
}

// async global->LDS, 16B per lane, dest = wave-uniform base + lane*16
__device__ __forceinline__ void stage16(const short* g, short* l) {
    __builtin_amdgcn_global_load_lds(
        (const __attribute__((address_space(1))) unsigned int*)g,
        (__attribute__((address_space(3))) unsigned int*)l, 16, 0, 0);
}

// ---------------------------------------------------------------------------
// Kernel 0: weights fp32->bf16 + mask-bias table. 448 blocks x 256.
// ---------------------------------------------------------------------------
__global__ __launch_bounds__(256) void prep_kernel(
    const float* __restrict__ wq, const float* __restrict__ wk,
    const float* __restrict__ wv, const unsigned char* __restrict__ xmask,
    short* __restrict__ wb, float* __restrict__ mbg)
{
    if (blockIdx.x < 192) {
        int idx = blockIdx.x * 256 + threadIdx.x;
        int mat = idx >> 14, off = idx & 16383;
        const float* src = (mat == 0) ? wq : ((mat == 1) ? wk : wv);
        float4_t v = *(const float4_t*)(src + (long)off * 4);
        short4_t o;
#pragma unroll
        for (int j = 0; j < 4; j++) o[j] = f2bt(v[j]);
        *(short4_t*)(wb + (long)idx * 4) = o;
    } else {
        int idx = (blockIdx.x - 192) * 256 + threadIdx.x;   // 0..65535
        int bc = idx >> 10, t = idx & 1023;
        int b = bc >> 4, c = bc & 15;
        mbg[idx] = xmask[((long)b * 1024 + t) * 16 + c] ? -1e30f : 0.0f;
    }
}

// ---------------------------------------------------------------------------
// Kernel 1: MFMA QKV projection + rotary (unchanged).
// ---------------------------------------------------------------------------
__global__ __launch_bounds__(256) void qkv_mfma_kernel(
    const float* __restrict__ x, const int* __restrict__ pos,
    const float* __restrict__ pe, const short* __restrict__ wb,
    const float* __restrict__ bq, const float* __restrict__ bk,
    const float* __restrict__ bv,
    short* __restrict__ qo, short* __restrict__ ko, short* __restrict__ vt)
{
    __shared__ __align__(16) short xs[64 * 264];
    __shared__ __align__(16) short ys[18432];
    __shared__ int posb[64];

    const int tid = threadIdx.x;
    const int lane = tid & 63;
    const int wid = tid >> 6;
    const int bc = blockIdx.x >> 4;
    const int t0 = (blockIdx.x & 15) * 64;
    const int b = bc >> 4, c = bc & 15;
    const int row = lane & 15, quad = lane >> 4;
    const int odd = lane & 1;
    const int n0 = wid * 64;
    const long kvbase = (long)bc * 262144;

#pragma unroll
    for (int j = 0; j < 8; j++) {
        int idx = tid + j * 256;
        int r = idx >> 5, c8 = idx & 31;
        const float* xp = x + (((long)b * 1024 + t0 + r) * 16 + c) * 256 + c8 * 8;
        float4_t a = *(const float4_t*)xp;
        float4_t d = *(const float4_t*)(xp + 4);
        short8_t o;
        o[0] = f2bt(a.x); o[1] = f2bt(a.y); o[2] = f2bt(a.z); o[3] = f2bt(a.w);
        o[4] = f2bt(d.x); o[5] = f2bt(d.y); o[6] = f2bt(d.z); o[7] = f2bt(d.w);
        *(short8_t*)&xs[r * 264 + c8 * 8] = o;
    }
    if (tid < 64) posb[tid] = pos[((long)b * 1024 + t0 + tid) * 16 + c];
    __syncthreads();

#pragma unroll 1
    for (int mat = 0; mat < 3; mat++) {
        const short* W = wb + mat * 65536;
        float4_t acc[4][4];
#pragma unroll
        for (int mt = 0; mt < 4; mt++)
#pragma unroll
            for (int nt = 0; nt < 4; nt++) acc[mt][nt] = (float4_t){0.f, 0.f, 0.f, 0.f};

        short8_t Ac[4], Bc[4], An[4], Bn[4];
        auto loadA = [&](short8_t* A, int k0) {
#pragma unroll
            for (int mt = 0; mt < 4; mt++)
                A[mt] = *(const short8_t*)&xs[(mt * 16 + row) * 264 + k0 * 32 + quad * 8];
        };
        auto loadB = [&](short8_t* Bf, int k0) {
#pragma unroll
            for (int nt = 0; nt < 4; nt++)
                Bf[nt] = *(const short8_t*)(W + (n0 + nt * 16 + row) * 256 + k0 * 32 + quad * 8);
        };
        loadA(Ac, 0); loadB(Bc, 0);
#pragma unroll
        for (int k0 = 0; k0 < 8; k0++) {
            if (k0 < 7) { loadA(An, k0 + 1); loadB(Bn, k0 + 1); }
#pragma unroll
            for (int mt = 0; mt < 4; mt++)
#pragma unroll
                for (int nt = 0; nt < 4; nt++)
                    acc[mt][nt] = __builtin_amdgcn_mfma_f32_16x16x32_bf16(
                        Ac[mt], Bc[nt], acc[mt][nt], 0, 0, 0);
            if (k0 < 7) {
#pragma unroll
                for (int i = 0; i < 4; i++) { Ac[i] = An[i]; Bc[i] = Bn[i]; }
            }
        }

        const float* bias = (mat == 0) ? bq : ((mat == 1) ? bk : bv);
        float bs[4];
#pragma unroll
        for (int nt = 0; nt < 4; nt++) bs[nt] = bias[n0 + nt * 16 + row];
#pragma unroll
        for (int mt = 0; mt < 4; mt++)
#pragma unroll
            for (int nt = 0; nt < 4; nt++)
#pragma unroll
                for (int r = 0; r < 4; r++) acc[mt][nt][r] += bs[nt];

        if (mat < 2) {
#pragma unroll
            for (int mt = 0; mt < 4; mt++)
#pragma unroll
                for (int r = 0; r < 4; r++) {
                    int p = posb[mt * 16 + quad * 4 + r];
                    const float* pb = pe + (long)p * 256;
#pragma unroll
                    for (int nt = 0; nt < 4; nt++) {
                        int i = (n0 + nt * 16 + row) >> 1;
                        float2_t cs = *(const float2_t*)(pb + i * 2);
                        float v = acc[mt][nt][r];
                        float pr = __shfl_xor(v, 1);
                        acc[mt][nt][r] = v * cs.x + pr * (odd ? cs.y : -cs.y);
                    }
                }
        }

        __syncthreads();
        if (mat < 2) {
#pragma unroll
            for (int mt = 0; mt < 4; mt++)
#pragma unroll
                for (int nt = 0; nt < 4; nt++) {
                    int n = n0 + nt * 16 + row;
#pragma unroll
                    for (int r = 0; r < 4; r++)
                        ys[(mt * 16 + quad * 4 + r) * 264 + n] = f2bt(acc[mt][nt][r]);
                }
            __syncthreads();
            short* dst = ((mat == 0) ? qo : ko) + kvbase + (long)t0 * 256;
#pragma unroll
            for (int j = 0; j < 8; j++) {
                int idx = tid + j * 256;
                int r = idx >> 5, c8 = idx & 31;
                *(short8_t*)(dst + r * 256 + c8 * 8) = *(const short8_t*)&ys[r * 264 + c8 * 8];
            }
        } else {
#pragma unroll
            for (int mt = 0; mt < 4; mt++)
#pragma unroll
                for (int nt = 0; nt < 4; nt++) {
                    int n = n0 + nt * 16 + row;
                    short4_t o4;
#pragma unroll
                    for (int r = 0; r < 4; r++) o4[r] = f2bt(acc[mt][nt][r]);
                    *(short4_t*)&ys[n * 72 + mt * 16 + quad * 4] = o4;
                }
            __syncthreads();
#pragma unroll
            for (int j = 0; j < 8; j++) {
                int idx = tid + j * 256;
                int d = idx >> 3, t8 = idx & 7;
                *(short8_t*)(vt + kvbase + (long)d * 1024 + t0 + t8 * 8) =
                    *(const short8_t*)&ys[d * 72 + t8 * 8];
            }
        }
    }
}

// ---------------------------------------------------------------------------
// Kernel 2: flash attention. 512 thr, 8 waves x 32 q-rows (2 m-tiles) = 256
// q/block. K/V B-frags read from LDS once, reused by both m-tiles (halves
// LDS read traffic per FLOP). KV-tile 32, triple-buffered global_load_lds
// (counted vmcnt + raw s_barrier), online softmax w/ defer-max, in-reg LN.
// PT transpose stride 34 shorts (17 coprime 32 -> quads hit disjoint banks).
// LDS: K 3x16KB | V 3x16KB | PT 8x2176B | mask 4KB = ~117KB -> 1 block/CU.
// ---------------------------------------------------------------------------
__global__ __launch_bounds__(512, 2) void attn_kernel(
    const short* __restrict__ qg, const short* __restrict__ kg,
    const short* __restrict__ vt, const float* __restrict__ mbg,
    const float* __restrict__ x,
    const float* __restrict__ lsg, const float* __restrict__ lng,
    const float* __restrict__ lnb, float* __restrict__ out)
{
    __shared__ __align__(16) short lds[59904];   // 119808 B
    // shorts: Ks[buf<3] @ buf*8192 (row r*256, 16B slot s holds gcol-slot s^(r&7))
    //         Vs[buf<3] @ 24576+buf*8192 (row d*32, 4 slots, slot s = gslot^((d>>1)&3))
    //         PT[wave]  @ 49152+wid*1088 (32 k-rows x stride 34 shorts, q=0..31)
    //         mbs f32   @ 57856 (1024 floats)

    const int tid = threadIdx.x;
    const int lane = tid & 63;
    const int wid = tid >> 6;
    // 256 blocks, 8 XCDs: chunked swizzle -> 32 consecutive bids per XCD
    const int bid = (blockIdx.x & 7) * 32 + (blockIdx.x >> 3);
    const int bc = bid >> 2;
    const int tq0 = (bid & 3) * 256;
    const int b = bc >> 4, c = bc & 15;
    const long kvbase = (long)bc * 262144;
    const int bcq = bc * 1024;
    const int row = lane & 15, quad = lane >> 4;
    float* mbsf = (float*)&lds[57856];

    auto stage = [&](int j, int buf) {
#pragma unroll
        for (int i = 0; i < 2; i++) {            // K tile: 32 rows x 512B
            int rp = (wid * 2 + i) * 2;
            int r = rp + (lane >> 5);
            int slot = lane & 31;
            const short* g = kg + kvbase + (long)(j * 32 + r) * 256 +
                             ((slot ^ (r & 7)) << 3);
            stage16(g, &lds[buf * 8192 + rp * 256]);
        }
#pragma unroll
        for (int i = 0; i < 2; i++) {            // V tile: 256 d-rows x 64B
            int db = (wid * 2 + i) * 16;
            int d = db + (lane >> 2);
            int slot = lane & 3;
            const short* g = vt + kvbase + (long)d * 1024 + j * 32 +
                             (((slot ^ ((d >> 1) & 3))) << 3);
            stage16(g, &lds[24576 + buf * 8192 + db * 32]);
        }
    };

    // ---- prologue: stage tiles 0,1; mask row -> LDS; Q frags -> regs ----
    stage(0, 0);
    stage(1, 1);
#pragma unroll
    for (int i = tid; i < 1024; i += 512) mbsf[i] = mbg[bcq + i];
    short8_t aq[2][8];
#pragma unroll
    for (int mt = 0; mt < 2; mt++)
#pragma unroll
        for (int f = 0; f < 8; f++)
            aq[mt][f] = *(const short8_t*)(qg + kvbase +
                (long)(tq0 + wid * 32 + mt * 16 + row) * 256 + f * 32 + quad * 8);

    float4_t oacc[2][16];
#pragma unroll
    for (int mt = 0; mt < 2; mt++)
#pragma unroll
        for (int nt = 0; nt < 16; nt++) oacc[mt][nt] = (float4_t){0.f, 0.f, 0.f, 0.f};
    float m[2][4], lsum[2][4];
#pragma unroll
    for (int mt = 0; mt < 2; mt++)
#pragma unroll
        for (int r = 0; r < 4; r++) { m[mt][r] = -__builtin_inff(); lsum[mt][r] = 0.f; }

    const float scale = 0.0625f;
    const int PTB = 49152 + wid * 1088;

    asm volatile("s_waitcnt lgkmcnt(0)" ::: "memory");   // mbs ds_writes done

    int bcur = 0;
#pragma unroll 1
    for (int j = 0; j < 32; j++) {
        int bnx = bcur + 2; if (bnx >= 3) bnx -= 3;
        if (j < 30) {
            stage(j + 2, bnx);
            asm volatile("s_waitcnt vmcnt(8)" ::: "memory");
        } else if (j == 30) {
            asm volatile("s_waitcnt vmcnt(4)" ::: "memory");
        } else {
            asm volatile("s_waitcnt vmcnt(0)" ::: "memory");
        }
        __builtin_amdgcn_s_barrier();                    // tile j staged for all waves

        const short* Kb = &lds[bcur * 8192];
        const short* Vb = &lds[24576 + bcur * 8192];

        // S = Q K^T : 2 m-tiles x 2 k-tiles, K-frags loaded once, reused
        float4_t s00 = {0.f,0.f,0.f,0.f}, s01 = {0.f,0.f,0.f,0.f};
        float4_t s10 = {0.f,0.f,0.f,0.f}, s11 = {0.f,0.f,0.f,0.f};
#pragma unroll
        for (int f = 0; f < 8; f++) {
            short8_t k0 = *(const short8_t*)&Kb[row * 256 + (((f * 4 + quad) ^ (row & 7)) << 3)];
            short8_t k1 = *(const short8_t*)&Kb[(16 + row) * 256 + (((f * 4 + quad) ^ ((16 + row) & 7)) << 3)];
            s00 = __builtin_amdgcn_mfma_f32_16x16x32_bf16(aq[0][f], k0, s00, 0, 0, 0);
            s01 = __builtin_amdgcn_mfma_f32_16x16x32_bf16(aq[0][f], k1, s01, 0, 0, 0);
            s10 = __builtin_amdgcn_mfma_f32_16x16x32_bf16(aq[1][f], k0, s10, 0, 0, 0);
            s11 = __builtin_amdgcn_mfma_f32_16x16x32_bf16(aq[1][f], k1, s11, 0, 0, 0);
        }
        float mb0 = mbsf[j * 32 + row], mb1 = mbsf[j * 32 + 16 + row];
        float tm[2][4];
#pragma unroll
        for (int r = 0; r < 4; r++) {
            s00[r] = s00[r] * scale + mb0;  s01[r] = s01[r] * scale + mb1;
            s10[r] = s10[r] * scale + mb0;  s11[r] = s11[r] * scale + mb1;
            tm[0][r] = fmaxf(s00[r], s01[r]);
            tm[1][r] = fmaxf(s10[r], s11[r]);
        }
#pragma unroll
        for (int mt = 0; mt < 2; mt++)
#pragma unroll
            for (int r = 0; r < 4; r++)
#pragma unroll
                for (int o = 1; o < 16; o <<= 1)
                    tm[mt][r] = fmaxf(tm[mt][r], __shfl_xor(tm[mt][r], o));
        float g = fmaxf(
            fmaxf(fmaxf(tm[0][0] - m[0][0], tm[0][1] - m[0][1]),
                  fmaxf(tm[0][2] - m[0][2], tm[0][3] - m[0][3])),
            fmaxf(fmaxf(tm[1][0] - m[1][0], tm[1][1] - m[1][1]),
                  fmaxf(tm[1][2] - m[1][2], tm[1][3] - m[1][3])));
        if (!__all(g <= 8.f)) {                          // rescale (rare: defer-max)
#pragma unroll
            for (int mt = 0; mt < 2; mt++)
#pragma unroll
                for (int r = 0; r < 4; r++) {
                    float nm = fmaxf(m[mt][r], tm[mt][r]);
                    float fac = __expf(m[mt][r] - nm);
                    lsum[mt][r] *= fac; m[mt][r] = nm;
#pragma unroll
                    for (int nt = 0; nt < 16; nt++) oacc[mt][nt][r] *= fac;
                }
        }
        // P = exp(S - m) -> PT (stride-34 transpose buffer)
        {
            short4_t pk0, pk1;
#pragma unroll
            for (int r = 0; r < 4; r++) {
                float p0 = __expf(s00[r] - m[0][r]); lsum[0][r] += p0; pk0[r] = f2bt(p0);
                float p1 = __expf(s01[r] - m[0][r]); lsum[0][r] += p1; pk1[r] = f2bt(p1);
            }
            *(short4_t*)&lds[PTB + row * 34 + quad * 4] = pk0;
            *(short4_t*)&lds[PTB + (16 + row) * 34 + quad * 4] = pk1;
#pragma unroll
            for (int r = 0; r < 4; r++) {
                float p0 = __expf(s10[r] - m[1][r]); lsum[1][r] += p0; pk0[r] = f2bt(p0);
                float p1 = __expf(s11[r] - m[1][r]); lsum[1][r] += p1; pk1[r] = f2bt(p1);
            }
            *(short4_t*)&lds[PTB + row * 34 + 16 + quad * 4] = pk0;
            *(short4_t*)&lds[PTB + (16 + row) * 34 + 16 + quad * 4] = pk1;
        }
        short8_t pa[2];
#pragma unroll
        for (int mt = 0; mt < 2; mt++)
#pragma unroll
            for (int jj = 0; jj < 8; jj++)
                pa[mt][jj] = lds[PTB + (quad * 8 + jj) * 34 + mt * 16 + row];

        // O += P V : V-frags loaded once, reused by both m-tiles
#pragma unroll
        for (int nt = 0; nt < 16; nt++) {
            int d = nt * 16 + row;
            short8_t vbf = *(const short8_t*)&Vb[d * 32 + ((quad ^ ((d >> 1) & 3)) << 3)];
            oacc[0][nt] = __builtin_amdgcn_mfma_f32_16x16x32_bf16(pa[0], vbf, oacc[0][nt], 0, 0, 0);
            oacc[1][nt] = __builtin_amdgcn_mfma_f32_16x16x32_bf16(pa[1], vbf, oacc[1][nt], 0, 0, 0);
        }

        asm volatile("s_waitcnt lgkmcnt(0)" ::: "memory");
        __builtin_amdgcn_s_barrier();                    // buf reads done -> reusable
        bcur++; if (bcur >= 3) bcur = 0;
    }

    // ---- epilogue: finish softmax norm; y = x + ls*o; LayerNorm; store ----
    float inv[2][4];
#pragma unroll
    for (int mt = 0; mt < 2; mt++)
#pragma unroll
        for (int r = 0; r < 4; r++) {
            float s = lsum[mt][r];
#pragma unroll
            for (int o = 1; o < 16; o <<= 1) s += __shfl_xor(s, o);
            int qi = tq0 + wid * 32 + mt * 16 + quad * 4 + r;
            inv[mt][r] = (mbsf[qi] != 0.f) ? 0.f : (1.f / s);
        }
    long xb[2][4];
#pragma unroll
    for (int mt = 0; mt < 2; mt++)
#pragma unroll
        for (int r = 0; r < 4; r++)
            xb[mt][r] = (((long)b * 1024 + tq0 + wid * 32 + mt * 16 + quad * 4 + r) * 16 + c) * 256 + row;

    float s1r[2][4] = {{0.f,0.f,0.f,0.f},{0.f,0.f,0.f,0.f}};
    float s2r[2][4] = {{0.f,0.f,0.f,0.f},{0.f,0.f,0.f,0.f}};
#pragma unroll
    for (int nt = 0; nt < 16; nt++) {
        int d = nt * 16 + row;
        float lg = lsg[d];
#pragma unroll
        for (int mt = 0; mt < 2; mt++)
#pragma unroll
            for (int r = 0; r < 4; r++) {
                float yy = x[xb[mt][r] + nt * 16] + lg * (oacc[mt][nt][r] * inv[mt][r]);
                oacc[mt][nt][r] = yy;
                s1r[mt][r] += yy; s2r[mt][r] += yy * yy;
            }
    }
    float mu[2][4], rstd[2][4];
#pragma unroll
    for (int mt = 0; mt < 2; mt++)
#pragma unroll
        for (int r = 0; r < 4; r++) {
#pragma unroll
            for (int o = 1; o < 16; o <<= 1) {
                s1r[mt][r] += __shfl_xor(s1r[mt][r], o);
                s2r[mt][r] += __shfl_xor(s2r[mt][r], o);
            }
            mu[mt][r] = s1r[mt][r] * (1.f / 256.f);
            float var = s2r[mt][r] * (1.f / 256.f) - mu[mt][r] * mu[mt][r];
            rstd[mt][r] = rsqrtf(var + 1e-5f);
        }
#pragma unroll
    for (int nt = 0; nt < 16; nt++) {
        int d = nt * 16 + row;
        float g2 = lng[d], b2 = lnb[d];
#pragma unroll
        for (int mt = 0; mt < 2; mt++)
#pragma unroll
            for (int r = 0; r < 4; r++)
                out[xb[mt][r] + nt * 16] = (oacc[mt][nt][r] - mu[mt][r]) * rstd[mt][r] * g2 + b2;
    }
}

// ---------------------------------------------------------------------------
extern "C" void kernel_launch(void* const* d_in, const int* in_sizes, int n_in,
                              void* d_out, int out_size, void* d_ws, size_t ws_size,
                              hipStream_t stream) {
    const float* x = (const float*)d_in[0];
    const unsigned char* xmask = (const unsigned char*)d_in[1];
    const int* pos = (const int*)d_in[2];
    const float* pe = (const float*)d_in[3];
    const float* wq = (const float*)d_in[4];
    const float* bq = (const float*)d_in[5];
    const float* wk = (const float*)d_in[6];
    const float* bk = (const float*)d_in[7];
    const float* wv = (const float*)d_in[8];
    const float* bv = (const float*)d_in[9];
    const float* lng = (const float*)d_in[10];
    const float* lnb = (const float*)d_in[11];
    const float* lsg = (const float*)d_in[12];
    float* out = (float*)d_out;

    short* qw = (short*)d_ws;              // 32MB
    short* kw = qw + 16777216;             // 32MB
    short* vtw = kw + 16777216;            // 32MB
    short* wbw = vtw + 16777216;           // 384KB
    float* mbg = (float*)(wbw + 196608);   // 256KB mask bias

    prep_kernel<<<448, 256, 0, stream>>>(wq, wk, wv, xmask, wbw, mbg);
    qkv_mfma_kernel<<<1024, 256, 0, stream>>>(x, pos, pe, wbw, bq, bk, bv,
                                              qw, kw, vtw);
    attn_kernel<<<256, 512, 0, stream>>>(qw, kw, vtw, mbg, x, lsg, lng, lnb, out);
}